// Round 1
// baseline (366.088 us; speedup 1.0000x reference)
//
#include <hip/hip_runtime.h>

#define B_SZ 16
#define S_SZ 8192
#define H_SZ 256

typedef _Float16 half8 __attribute__((ext_vector_type(8)));
typedef float f32x4 __attribute__((ext_vector_type(4)));

__device__ __forceinline__ float tanh_fast(float x) {
  // tanh(x) = 1 - 2/(e^{2x}+1); handles +-inf saturation correctly.
  float e = __expf(2.0f * x);
  return 1.0f - 2.0f / (e + 1.0f);
}

// ---------------------------------------------------------------------------
// Phase A: qb[b,o] = dot(query[b,:], Wq[o,:]) + b_attn[o]   (written into the
// context slot of d_out, which is memset to 0 later, after scores consumes it)
// ---------------------------------------------------------------------------
__global__ __launch_bounds__(256) void prep_kernel(
    const float* __restrict__ query, const float* __restrict__ W_attn,
    const float* __restrict__ b_attn, float* __restrict__ qb) {
  const int b = blockIdx.x;
  const int o = threadIdx.x;
  const float4* q4 = (const float4*)(query + b * H_SZ);
  const float4* w4 = (const float4*)(W_attn + (size_t)o * 512);  // Wq row o
  float acc = b_attn[o];
#pragma unroll 8
  for (int i = 0; i < 64; i++) {
    float4 qq = q4[i];
    float4 ww = w4[i];
    acc += qq.x * ww.x + qq.y * ww.y + qq.z * ww.z + qq.w * ww.w;
  }
  qb[b * H_SZ + o] = acc;
}

// ---------------------------------------------------------------------------
// Phase B: scores[r] = sum_o v[o] * tanh(qb[b,o] + key[r,:].Wk[o,:])
// 512 threads = 8 waves, 16 rows/wave -> 128 rows/block, 1024 blocks.
// Wk staged to LDS as f16 in 4 chunks of 64 o-rows (pitch 264 f16).
// ---------------------------------------------------------------------------
__global__ __launch_bounds__(512, 8) void scores_kernel(
    const float* __restrict__ key, const float* __restrict__ W_attn,
    const float* __restrict__ qb, const float* __restrict__ vvec,
    float* __restrict__ scores) {
  __shared__ _Float16 lds[64 * 264];

  const int tid = threadIdx.x;
  const int wid = tid >> 6;
  const int lane = tid & 63;
  const int n = lane & 15;     // MFMA column (o within tile)
  const int quad = lane >> 4;  // k-subgroup
  const int rowBase = blockIdx.x * 128;
  const int b = rowBase >> 13;  // 8192 rows per batch; 128 | 8192
  const int r = rowBase + wid * 16 + n;

  // Preload A fragments (this wave's 16 key rows, all 8 K-steps), f32 -> f16.
  // A[m = lane&15][k = quad*8 + j], k absolute = ks*32 + quad*8 + j.
  const float* krow = key + (size_t)r * H_SZ + quad * 8;
  half8 afrag[8];
#pragma unroll
  for (int ks = 0; ks < 8; ks++) {
    const float4* p = (const float4*)(krow + ks * 32);
    float4 f0 = p[0];
    float4 f1 = p[1];
    half8 a;
    a[0] = (_Float16)f0.x; a[1] = (_Float16)f0.y;
    a[2] = (_Float16)f0.z; a[3] = (_Float16)f0.w;
    a[4] = (_Float16)f1.x; a[5] = (_Float16)f1.y;
    a[6] = (_Float16)f1.z; a[7] = (_Float16)f1.w;
    afrag[ks] = a;
  }

  // Per-lane epilogue constants: o = tt*16 + n for tt in [0,16)
  float qb_all[16], v_all[16];
#pragma unroll
  for (int tt = 0; tt < 16; tt++) {
    qb_all[tt] = qb[b * H_SZ + tt * 16 + n];
    v_all[tt] = vvec[tt * 16 + n];
  }

  float score[4] = {0.f, 0.f, 0.f, 0.f};

  for (int c = 0; c < 4; c++) {
    __syncthreads();  // previous chunk's LDS reads done
    // Stage Wk chunk: o in [c*64, c*64+64), Wk[o,h] = W_attn[o*512 + 256 + h]
    for (int idx = tid; idx < 2048; idx += 512) {
      int row = idx >> 5, seg = idx & 31;
      const float4* src =
          (const float4*)(W_attn + (size_t)(c * 64 + row) * 512 + 256 + seg * 8);
      float4 f0 = src[0];
      float4 f1 = src[1];
      half8 h;
      h[0] = (_Float16)f0.x; h[1] = (_Float16)f0.y;
      h[2] = (_Float16)f0.z; h[3] = (_Float16)f0.w;
      h[4] = (_Float16)f1.x; h[5] = (_Float16)f1.y;
      h[6] = (_Float16)f1.z; h[7] = (_Float16)f1.w;
      *(half8*)&lds[row * 264 + seg * 8] = h;
    }
    __syncthreads();

    f32x4 acc[4];
#pragma unroll
    for (int t = 0; t < 4; t++) {
      f32x4 z = {0.f, 0.f, 0.f, 0.f};
      acc[t] = z;
    }

#pragma unroll
    for (int ks = 0; ks < 8; ks++) {
#pragma unroll
      for (int t = 0; t < 4; t++) {
        // B[k][n] = Wk[o = t*16+n][k]; same (quad,j)->k map as A.
        half8 bfrag =
            *(const half8*)&lds[(t * 16 + n) * 264 + ks * 32 + quad * 8];
        acc[t] = __builtin_amdgcn_mfma_f32_16x16x32_f16(afrag[ks], bfrag,
                                                        acc[t], 0, 0, 0);
      }
    }

    // Fold this chunk into the running score: C/D row m = quad*4+reg, col = n.
#pragma unroll
    for (int t = 0; t < 4; t++) {
      const int tt = c * 4 + t;
#pragma unroll
      for (int rg = 0; rg < 4; rg++) {
        float hv = tanh_fast(qb_all[tt] + acc[t][rg]);
        score[rg] = fmaf(v_all[tt], hv, score[rg]);
      }
    }
  }

  // Sum over the 16 lanes that hold different o-columns (same row m).
#pragma unroll
  for (int rg = 0; rg < 4; rg++) {
#pragma unroll
    for (int m = 8; m >= 1; m >>= 1)
      score[rg] += __shfl_xor(score[rg], m, 64);
  }
  if (n == 0) {
#pragma unroll
    for (int rg = 0; rg < 4; rg++)
      scores[rowBase + wid * 16 + quad * 4 + rg] = score[rg];
  }
}

// ---------------------------------------------------------------------------
// Phase C: in-place softmax over S=8192 per batch. 16 blocks x 1024 threads.
// ---------------------------------------------------------------------------
__global__ __launch_bounds__(1024) void softmax_kernel(float* __restrict__ attn) {
  const int b = blockIdx.x;
  const int tid = threadIdx.x;
  float* w = attn + b * S_SZ;

  float vals[8];
  float m = -1e30f;
#pragma unroll
  for (int i = 0; i < 8; i++) {
    vals[i] = w[tid + (i << 10)];
    m = fmaxf(m, vals[i]);
  }
#pragma unroll
  for (int off = 32; off >= 1; off >>= 1) m = fmaxf(m, __shfl_xor(m, off, 64));

  __shared__ float red[16];
  __shared__ float bcast[2];
  const int wid = tid >> 6;
  const int lane = tid & 63;
  if (lane == 0) red[wid] = m;
  __syncthreads();
  if (wid == 0) {
    float mm = red[lane & 15];
#pragma unroll
    for (int off = 8; off >= 1; off >>= 1) mm = fmaxf(mm, __shfl_xor(mm, off, 64));
    if (lane == 0) bcast[0] = mm;
  }
  __syncthreads();
  m = bcast[0];

  float sum = 0.f;
#pragma unroll
  for (int i = 0; i < 8; i++) {
    vals[i] = __expf(vals[i] - m);
    sum += vals[i];
  }
#pragma unroll
  for (int off = 32; off >= 1; off >>= 1) sum += __shfl_xor(sum, off, 64);
  if (lane == 0) red[wid] = sum;
  __syncthreads();
  if (wid == 0) {
    float ss = red[lane & 15];
#pragma unroll
    for (int off = 8; off >= 1; off >>= 1) ss += __shfl_xor(ss, off, 64);
    if (lane == 0) bcast[1] = ss;
  }
  __syncthreads();
  const float inv = 1.0f / bcast[1];
#pragma unroll
  for (int i = 0; i < 8; i++) w[tid + (i << 10)] = vals[i] * inv;
}

// ---------------------------------------------------------------------------
// Phase D: context[b,h] = sum_s w[b,s] * value[b,s,h]. Grid (16, 64), each
// block handles 128 s-rows; perfectly coalesced value reads; atomicAdd fold.
// ---------------------------------------------------------------------------
__global__ __launch_bounds__(256) void context_kernel(
    const float* __restrict__ attn, const float* __restrict__ value,
    float* __restrict__ ctx) {
  const int b = blockIdx.x;
  const int j = blockIdx.y;
  const int h = threadIdx.x;
  const int s0 = j * 128;
  const float* w = attn + b * S_SZ + s0;
  const float* vp = value + ((size_t)(b * S_SZ + s0)) * H_SZ + h;
  float acc = 0.f;
#pragma unroll 8
  for (int s = 0; s < 128; s++) acc = fmaf(w[s], vp[(size_t)s * H_SZ], acc);
  atomicAdd(&ctx[b * H_SZ + h], acc);
}

// ---------------------------------------------------------------------------
extern "C" void kernel_launch(void* const* d_in, const int* in_sizes, int n_in,
                              void* d_out, int out_size, void* d_ws,
                              size_t ws_size, hipStream_t stream) {
  const float* query = (const float*)d_in[0];   // (16,1,256)
  const float* key = (const float*)d_in[1];     // (16,8192,256)
  const float* value = (const float*)d_in[2];   // (16,8192,256)
  const float* W_attn = (const float*)d_in[3];  // (256,512)
  const float* b_attn = (const float*)d_in[4];  // (256,)
  const float* vvec = (const float*)d_in[5];    // (256,)

  float* out = (float*)d_out;
  float* ctx = out;              // 16*256 = 4096 floats
  float* attn = out + 4096;      // 16*8192 = 131072 floats

  // qb scratch lives in the (not-yet-needed) context slot of d_out.
  prep_kernel<<<B_SZ, 256, 0, stream>>>(query, W_attn, b_attn, ctx);
  scores_kernel<<<1024, 512, 0, stream>>>(key, W_attn, ctx, vvec, attn);
  // qb consumed; zero the context slot for the atomic fold.
  hipMemsetAsync(ctx, 0, 4096 * sizeof(float), stream);
  softmax_kernel<<<B_SZ, 1024, 0, stream>>>(attn);
  context_kernel<<<dim3(B_SZ, 64), 256, 0, stream>>>(attn, value, ctx);
}

// Round 2
// 339.301 us; speedup vs baseline: 1.0789x; 1.0789x over previous
//
#include <hip/hip_runtime.h>

#define B_SZ 16
#define S_SZ 8192
#define H_SZ 256

typedef _Float16 half8 __attribute__((ext_vector_type(8)));
typedef float f32x4 __attribute__((ext_vector_type(4)));

__device__ __forceinline__ float tanh_fast(float x) {
  // tanh(x) = 1 - 2/(e^{2x}+1); handles +-inf saturation correctly.
  float e = __expf(2.0f * x);
  return 1.0f - 2.0f / (e + 1.0f);
}

// ---------------------------------------------------------------------------
// Phase A: qb[b,o] = dot(query[b,:], Wq[o,:]) + b_attn[o]
// Wave-per-o-row: 64 lanes load one contiguous 1 KiB W row (coalesced),
// dot4 + 6-level shuffle reduce. Grid (16, 4): block (b, jo) covers 64 o.
// ---------------------------------------------------------------------------
__global__ __launch_bounds__(256) void prep_kernel(
    const float* __restrict__ query, const float* __restrict__ W_attn,
    const float* __restrict__ b_attn, float* __restrict__ qb) {
  const int b = blockIdx.x;
  const int jo = blockIdx.y;
  const int wid = threadIdx.x >> 6;
  const int lane = threadIdx.x & 63;
  const float4 q4 = *(const float4*)(query + b * H_SZ + lane * 4);
#pragma unroll 4
  for (int i = 0; i < 16; i++) {
    const int o = jo * 64 + wid * 16 + i;
    const float4 w = *(const float4*)(W_attn + (size_t)o * 512 + lane * 4);
    float p = q4.x * w.x + q4.y * w.y + q4.z * w.z + q4.w * w.w;
#pragma unroll
    for (int off = 32; off >= 1; off >>= 1) p += __shfl_xor(p, off, 64);
    if (lane == 0) qb[b * H_SZ + o] = p + b_attn[o];
  }
}

// ---------------------------------------------------------------------------
// Phase B: scores[r] = sum_o v[o] * tanh(qb[b,o] + key[r,:].Wk[o,:])
// 512 threads = 8 waves, 16 rows/wave -> 128 rows/block, 1024 blocks.
// Wk staged to LDS as f16 in 4 chunks of 64 o-rows (pitch 264 f16).
// launch_bounds (512,4): 128-VGPR cap, 2 blocks/CU — R1's (512,8) forced a
// 64-VGPR cap and spilled 156 MB to scratch.
// ---------------------------------------------------------------------------
__global__ __launch_bounds__(512, 4) void scores_kernel(
    const float* __restrict__ key, const float* __restrict__ W_attn,
    const float* __restrict__ qb, const float* __restrict__ vvec,
    float* __restrict__ scores) {
  __shared__ _Float16 lds[64 * 264];

  const int tid = threadIdx.x;
  const int wid = tid >> 6;
  const int lane = tid & 63;
  const int n = lane & 15;     // MFMA column (o within tile)
  const int quad = lane >> 4;  // k-subgroup
  const int rowBase = blockIdx.x * 128;
  const int b = rowBase >> 13;  // 8192 rows per batch; 128 | 8192
  const int r = rowBase + wid * 16 + n;

  // Preload A fragments (this wave's 16 key rows, all 8 K-steps), f32 -> f16.
  // A[m = lane&15][k = quad*8 + j], k absolute = ks*32 + quad*8 + j.
  const float* krow = key + (size_t)r * H_SZ + quad * 8;
  half8 afrag[8];
#pragma unroll
  for (int ks = 0; ks < 8; ks++) {
    const float4* p = (const float4*)(krow + ks * 32);
    float4 f0 = p[0];
    float4 f1 = p[1];
    half8 a;
    a[0] = (_Float16)f0.x; a[1] = (_Float16)f0.y;
    a[2] = (_Float16)f0.z; a[3] = (_Float16)f0.w;
    a[4] = (_Float16)f1.x; a[5] = (_Float16)f1.y;
    a[6] = (_Float16)f1.z; a[7] = (_Float16)f1.w;
    afrag[ks] = a;
  }

  float score[4] = {0.f, 0.f, 0.f, 0.f};

  for (int c = 0; c < 4; c++) {
    __syncthreads();  // previous chunk's LDS reads done
    // Stage Wk chunk: o in [c*64, c*64+64), Wk[o,h] = W_attn[o*512 + 256 + h]
    for (int idx = tid; idx < 2048; idx += 512) {
      int row = idx >> 5, seg = idx & 31;
      const float4* src =
          (const float4*)(W_attn + (size_t)(c * 64 + row) * 512 + 256 + seg * 8);
      float4 f0 = src[0];
      float4 f1 = src[1];
      half8 h;
      h[0] = (_Float16)f0.x; h[1] = (_Float16)f0.y;
      h[2] = (_Float16)f0.z; h[3] = (_Float16)f0.w;
      h[4] = (_Float16)f1.x; h[5] = (_Float16)f1.y;
      h[6] = (_Float16)f1.z; h[7] = (_Float16)f1.w;
      *(half8*)&lds[row * 264 + seg * 8] = h;
    }
    __syncthreads();

    f32x4 acc[4];
#pragma unroll
    for (int t = 0; t < 4; t++) {
      f32x4 z = {0.f, 0.f, 0.f, 0.f};
      acc[t] = z;
    }

#pragma unroll
    for (int ks = 0; ks < 8; ks++) {
#pragma unroll
      for (int t = 0; t < 4; t++) {
        // B[k][n] = Wk[o = t*16+n][k]; same (quad,j)->k map as A.
        half8 bfrag =
            *(const half8*)&lds[(t * 16 + n) * 264 + ks * 32 + quad * 8];
        acc[t] = __builtin_amdgcn_mfma_f32_16x16x32_f16(afrag[ks], bfrag,
                                                        acc[t], 0, 0, 0);
      }
    }

    // Fold this chunk into the running score: C/D row m = quad*4+reg, col = n.
    // Load the 4 qb/v values for this chunk here (keeps live regs low).
#pragma unroll
    for (int t = 0; t < 4; t++) {
      const int tt = c * 4 + t;
      const float qbv = qb[b * H_SZ + tt * 16 + n];
      const float vv = vvec[tt * 16 + n];
#pragma unroll
      for (int rg = 0; rg < 4; rg++) {
        float hv = tanh_fast(qbv + acc[t][rg]);
        score[rg] = fmaf(vv, hv, score[rg]);
      }
    }
  }

  // Sum over the 16 lanes that hold different o-columns (same row m).
#pragma unroll
  for (int rg = 0; rg < 4; rg++) {
#pragma unroll
    for (int m = 8; m >= 1; m >>= 1)
      score[rg] += __shfl_xor(score[rg], m, 64);
  }
  if (n == 0) {
#pragma unroll
    for (int rg = 0; rg < 4; rg++)
      scores[rowBase + wid * 16 + quad * 4 + rg] = score[rg];
  }
}

// ---------------------------------------------------------------------------
// Phase C: in-place softmax over S=8192 per batch. 16 blocks x 1024 threads.
// ---------------------------------------------------------------------------
__global__ __launch_bounds__(1024) void softmax_kernel(float* __restrict__ attn) {
  const int b = blockIdx.x;
  const int tid = threadIdx.x;
  float* w = attn + b * S_SZ;

  float vals[8];
  float m = -1e30f;
#pragma unroll
  for (int i = 0; i < 8; i++) {
    vals[i] = w[tid + (i << 10)];
    m = fmaxf(m, vals[i]);
  }
#pragma unroll
  for (int off = 32; off >= 1; off >>= 1) m = fmaxf(m, __shfl_xor(m, off, 64));

  __shared__ float red[16];
  __shared__ float bcast[2];
  const int wid = tid >> 6;
  const int lane = tid & 63;
  if (lane == 0) red[wid] = m;
  __syncthreads();
  if (wid == 0) {
    float mm = red[lane & 15];
#pragma unroll
    for (int off = 8; off >= 1; off >>= 1) mm = fmaxf(mm, __shfl_xor(mm, off, 64));
    if (lane == 0) bcast[0] = mm;
  }
  __syncthreads();
  m = bcast[0];

  float sum = 0.f;
#pragma unroll
  for (int i = 0; i < 8; i++) {
    vals[i] = __expf(vals[i] - m);
    sum += vals[i];
  }
#pragma unroll
  for (int off = 32; off >= 1; off >>= 1) sum += __shfl_xor(sum, off, 64);
  if (lane == 0) red[wid] = sum;
  __syncthreads();
  if (wid == 0) {
    float ss = red[lane & 15];
#pragma unroll
    for (int off = 8; off >= 1; off >>= 1) ss += __shfl_xor(ss, off, 64);
    if (lane == 0) bcast[1] = ss;
  }
  __syncthreads();
  const float inv = 1.0f / bcast[1];
#pragma unroll
  for (int i = 0; i < 8; i++) w[tid + (i << 10)] = vals[i] * inv;
}

// ---------------------------------------------------------------------------
// Phase D: context[b,h] = sum_s w[b,s] * value[b,s,h]. Grid (16, 64), each
// block handles 128 s-rows; perfectly coalesced value reads; atomicAdd fold.
// ---------------------------------------------------------------------------
__global__ __launch_bounds__(256) void context_kernel(
    const float* __restrict__ attn, const float* __restrict__ value,
    float* __restrict__ ctx) {
  const int b = blockIdx.x;
  const int j = blockIdx.y;
  const int h = threadIdx.x;
  const int s0 = j * 128;
  const float* w = attn + b * S_SZ + s0;
  const float* vp = value + ((size_t)(b * S_SZ + s0)) * H_SZ + h;
  float acc = 0.f;
#pragma unroll 8
  for (int s = 0; s < 128; s++) acc = fmaf(w[s], vp[(size_t)s * H_SZ], acc);
  atomicAdd(&ctx[b * H_SZ + h], acc);
}

// ---------------------------------------------------------------------------
extern "C" void kernel_launch(void* const* d_in, const int* in_sizes, int n_in,
                              void* d_out, int out_size, void* d_ws,
                              size_t ws_size, hipStream_t stream) {
  const float* query = (const float*)d_in[0];   // (16,1,256)
  const float* key = (const float*)d_in[1];     // (16,8192,256)
  const float* value = (const float*)d_in[2];   // (16,8192,256)
  const float* W_attn = (const float*)d_in[3];  // (256,512)
  const float* b_attn = (const float*)d_in[4];  // (256,)
  const float* vvec = (const float*)d_in[5];    // (256,)

  float* out = (float*)d_out;
  float* ctx = out;              // 16*256 = 4096 floats
  float* attn = out + 4096;      // 16*8192 = 131072 floats

  // qb scratch lives in the (not-yet-needed) context slot of d_out.
  prep_kernel<<<dim3(B_SZ, 4), 256, 0, stream>>>(query, W_attn, b_attn, ctx);
  scores_kernel<<<1024, 512, 0, stream>>>(key, W_attn, ctx, vvec, attn);
  // qb consumed; zero the context slot for the atomic fold.
  hipMemsetAsync(ctx, 0, 4096 * sizeof(float), stream);
  softmax_kernel<<<B_SZ, 1024, 0, stream>>>(attn);
  context_kernel<<<dim3(B_SZ, 64), 256, 0, stream>>>(attn, value, ctx);
}

// Round 3
// 336.558 us; speedup vs baseline: 1.0877x; 1.0082x over previous
//
#include <hip/hip_runtime.h>

#define B_SZ 16
#define S_SZ 8192
#define H_SZ 256

typedef _Float16 half8 __attribute__((ext_vector_type(8)));
typedef float f32x4 __attribute__((ext_vector_type(4)));

__device__ __forceinline__ float tanh_fast(float x) {
  // tanh(x) = 1 - 2/(e^{2x}+1); handles +-inf saturation correctly.
  float e = __expf(2.0f * x);
  return 1.0f - 2.0f / (e + 1.0f);
}

// ---------------------------------------------------------------------------
// Phase A: qb[b,o] = dot(query[b,:], Wq[o,:]) + b_attn[o]
// Wave-per-o-row: 64 lanes load one contiguous 1 KiB W row, shuffle-reduce.
// ---------------------------------------------------------------------------
__global__ __launch_bounds__(256) void prep_kernel(
    const float* __restrict__ query, const float* __restrict__ W_attn,
    const float* __restrict__ b_attn, float* __restrict__ qb) {
  const int b = blockIdx.x;
  const int jo = blockIdx.y;
  const int wid = threadIdx.x >> 6;
  const int lane = threadIdx.x & 63;
  const float4 q4 = *(const float4*)(query + b * H_SZ + lane * 4);
#pragma unroll 4
  for (int i = 0; i < 16; i++) {
    const int o = jo * 64 + wid * 16 + i;
    const float4 w = *(const float4*)(W_attn + (size_t)o * 512 + lane * 4);
    float p = q4.x * w.x + q4.y * w.y + q4.z * w.z + q4.w * w.w;
#pragma unroll
    for (int off = 32; off >= 1; off >>= 1) p += __shfl_xor(p, off, 64);
    if (lane == 0) qb[b * H_SZ + o] = p + b_attn[o];
  }
}

// ---------------------------------------------------------------------------
// Phase B (persistent): scores[r] = sum_o v[o]*tanh(qb[b,o] + key[r,:].Wk[o,:])
// 256 blocks x 1024 threads (1 block/CU, 16 waves). Wk staged as f16 in two
// 64 KiB chunks of 128 o-rows, pitch 256 halfs + XOR swizzle on the 16B seg
// index (conflict-minimal without padding). Each wave owns 32 key rows
// (2 row-tiles): every B fragment feeds 2 MFMAs -> half the LDS traffic.
// Only 3 barriers per block lifetime; compute loop is barrier-free.
// ---------------------------------------------------------------------------
__global__ __launch_bounds__(1024, 4) void scores_kernel(
    const float* __restrict__ key, const float* __restrict__ W_attn,
    const float* __restrict__ qb, const float* __restrict__ vvec,
    float* __restrict__ scores) {
  __shared__ _Float16 lds[128 * 256];  // 64 KiB

  const int tid = threadIdx.x;
  const int wid = tid >> 6;
  const int lane = tid & 63;
  const int n = lane & 15;     // MFMA column / A-row within tile
  const int quad = lane >> 4;  // k-subgroup
  const int wbase = (blockIdx.x * 16 + wid) * 32;  // 32 rows per wave
  const int b = wbase >> 13;   // 8192 rows per batch; 32 | 8192

  // Preload A fragments: 2 row-tiles x 8 K-steps, f32 -> f16.
  // A[m=lane&15][k=quad*8+j], k absolute = ks*32 + quad*8 + j.
  half8 afrag[2][8];
#pragma unroll
  for (int rt = 0; rt < 2; rt++) {
    const float* krow = key + (size_t)(wbase + rt * 16 + n) * H_SZ + quad * 8;
#pragma unroll
    for (int ks = 0; ks < 8; ks++) {
      const float4* p = (const float4*)(krow + ks * 32);
      float4 f0 = p[0];
      float4 f1 = p[1];
      half8 a;
      a[0] = (_Float16)f0.x; a[1] = (_Float16)f0.y;
      a[2] = (_Float16)f0.z; a[3] = (_Float16)f0.w;
      a[4] = (_Float16)f1.x; a[5] = (_Float16)f1.y;
      a[6] = (_Float16)f1.z; a[7] = (_Float16)f1.w;
      afrag[rt][ks] = a;
    }
  }

  float score[2][4] = {{0.f, 0.f, 0.f, 0.f}, {0.f, 0.f, 0.f, 0.f}};

  for (int c = 0; c < 2; c++) {
    if (c) __syncthreads();  // all waves done reading chunk 0
    // Stage Wk chunk c: o in [c*128, c*128+128). Wk[o,h] = W_attn[o*512+256+h]
    // Physical layout: lds[row*256 + (seg ^ (row&31))*8], seg = 16B segment.
#pragma unroll
    for (int it = 0; it < 4; it++) {
      int idx = tid + it * 1024;  // 128 rows * 32 segs = 4096
      int row = idx >> 5, seg = idx & 31;
      const float4* src =
          (const float4*)(W_attn + (size_t)(c * 128 + row) * 512 + 256 + seg * 8);
      float4 f0 = src[0];
      float4 f1 = src[1];
      half8 h;
      h[0] = (_Float16)f0.x; h[1] = (_Float16)f0.y;
      h[2] = (_Float16)f0.z; h[3] = (_Float16)f0.w;
      h[4] = (_Float16)f1.x; h[5] = (_Float16)f1.y;
      h[6] = (_Float16)f1.z; h[7] = (_Float16)f1.w;
      *(half8*)&lds[row * 256 + ((seg ^ (row & 31)) << 3)] = h;
    }
    __syncthreads();

    for (int trow = 0; trow < 8; trow++) {  // o-tile within chunk
      const int t = c * 8 + trow;           // global o-tile
      const int lrow = trow * 16 + n;       // B row within chunk (0..127)
      const int rl5 = lrow & 31;
      f32x4 acc0 = {0.f, 0.f, 0.f, 0.f};
      f32x4 acc1 = {0.f, 0.f, 0.f, 0.f};
#pragma unroll
      for (int ks = 0; ks < 8; ks++) {
        const int seg = ks * 4 + quad;
        half8 bfrag = *(const half8*)&lds[lrow * 256 + ((seg ^ rl5) << 3)];
        acc0 = __builtin_amdgcn_mfma_f32_16x16x32_f16(afrag[0][ks], bfrag,
                                                      acc0, 0, 0, 0);
        acc1 = __builtin_amdgcn_mfma_f32_16x16x32_f16(afrag[1][ks], bfrag,
                                                      acc1, 0, 0, 0);
      }
      const float qbv = qb[b * H_SZ + t * 16 + n];
      const float vv = vvec[t * 16 + n];
#pragma unroll
      for (int rg = 0; rg < 4; rg++) {
        score[0][rg] = fmaf(vv, tanh_fast(qbv + acc0[rg]), score[0][rg]);
        score[1][rg] = fmaf(vv, tanh_fast(qbv + acc1[rg]), score[1][rg]);
      }
    }
  }

  // Sum over the 16 lanes holding different o-columns (same output row).
#pragma unroll
  for (int rt = 0; rt < 2; rt++)
#pragma unroll
    for (int rg = 0; rg < 4; rg++)
#pragma unroll
      for (int m = 8; m >= 1; m >>= 1)
        score[rt][rg] += __shfl_xor(score[rt][rg], m, 64);
  if (n == 0) {
#pragma unroll
    for (int rt = 0; rt < 2; rt++)
#pragma unroll
      for (int rg = 0; rg < 4; rg++)
        scores[wbase + rt * 16 + quad * 4 + rg] = score[rt][rg];
  }
}

// ---------------------------------------------------------------------------
// Phase C: per-batch softmax stats. mz[2b] = max, mz[2b+1] = 1/sum(exp).
// Also zeroes the context slot (qb scratch already consumed by scores).
// ---------------------------------------------------------------------------
__global__ __launch_bounds__(1024) void reduce_kernel(
    const float* __restrict__ scores, float* __restrict__ mz,
    float* __restrict__ ctx) {
  const int b = blockIdx.x;
  const int tid = threadIdx.x;
  const float* s = scores + b * S_SZ;

  float vals[8];
  float m = -1e30f;
#pragma unroll
  for (int i = 0; i < 8; i++) {
    vals[i] = s[tid + (i << 10)];
    m = fmaxf(m, vals[i]);
  }
#pragma unroll
  for (int off = 32; off >= 1; off >>= 1) m = fmaxf(m, __shfl_xor(m, off, 64));

  __shared__ float red[16];
  __shared__ float bcast[2];
  const int wid = tid >> 6;
  const int lane = tid & 63;
  if (lane == 0) red[wid] = m;
  __syncthreads();
  if (wid == 0) {
    float mm = red[lane & 15];
#pragma unroll
    for (int off = 8; off >= 1; off >>= 1)
      mm = fmaxf(mm, __shfl_xor(mm, off, 64));
    if (lane == 0) bcast[0] = mm;
  }
  __syncthreads();
  m = bcast[0];

  float sum = 0.f;
#pragma unroll
  for (int i = 0; i < 8; i++) sum += __expf(vals[i] - m);
#pragma unroll
  for (int off = 32; off >= 1; off >>= 1) sum += __shfl_xor(sum, off, 64);
  if (lane == 0) red[wid] = sum;
  __syncthreads();
  if (wid == 0) {
    float ss = red[lane & 15];
#pragma unroll
    for (int off = 8; off >= 1; off >>= 1) ss += __shfl_xor(ss, off, 64);
    if (lane == 0) {
      bcast[1] = ss;
      mz[2 * b] = m;
      mz[2 * b + 1] = 1.0f / ss;
    }
  }
  // Zero context slot for the atomic fold (256 floats per batch).
  if (tid < H_SZ) ctx[b * H_SZ + tid] = 0.f;
}

// ---------------------------------------------------------------------------
// Phase D: w = exp(score-m)*invZ; write attn_weights in place; accumulate
// context[b,h] += sum_s w*value. Grid (16,32), 256 s-rows per block.
// ---------------------------------------------------------------------------
__global__ __launch_bounds__(256) void context_kernel(
    const float* __restrict__ mz, const float* __restrict__ value,
    float* __restrict__ attn, float* __restrict__ ctx) {
  __shared__ float wsm[256];
  const int b = blockIdx.x;
  const int j = blockIdx.y;
  const int h = threadIdx.x;
  const int s0 = j * 256;
  const float m = mz[2 * b];
  const float invZ = mz[2 * b + 1];
  float* arow = attn + b * S_SZ + s0;
  const float w = __expf(arow[h] - m) * invZ;
  arow[h] = w;  // attn_weights output
  wsm[h] = w;
  __syncthreads();
  const float* vp = value + ((size_t)(b * S_SZ + s0)) * H_SZ + h;
  float acc = 0.f;
#pragma unroll 8
  for (int s = 0; s < 256; s++) acc = fmaf(wsm[s], vp[(size_t)s * H_SZ], acc);
  atomicAdd(&ctx[b * H_SZ + h], acc);
}

// ---------------------------------------------------------------------------
extern "C" void kernel_launch(void* const* d_in, const int* in_sizes, int n_in,
                              void* d_out, int out_size, void* d_ws,
                              size_t ws_size, hipStream_t stream) {
  const float* query = (const float*)d_in[0];   // (16,1,256)
  const float* key = (const float*)d_in[1];     // (16,8192,256)
  const float* value = (const float*)d_in[2];   // (16,8192,256)
  const float* W_attn = (const float*)d_in[3];  // (256,512)
  const float* b_attn = (const float*)d_in[4];  // (256,)
  const float* vvec = (const float*)d_in[5];    // (256,)

  float* out = (float*)d_out;
  float* ctx = out;          // 16*256 = 4096 floats
  float* attn = out + 4096;  // 16*8192 = 131072 floats (raw scores -> weights)
  float* mz = (float*)d_ws;  // 32 floats: per-batch max, 1/Z

  // qb scratch lives in the (not-yet-needed) context slot of d_out.
  prep_kernel<<<dim3(B_SZ, 4), 256, 0, stream>>>(query, W_attn, b_attn, ctx);
  scores_kernel<<<256, 1024, 0, stream>>>(key, W_attn, ctx, vvec, attn);
  reduce_kernel<<<B_SZ, 1024, 0, stream>>>(attn, mz, ctx);
  context_kernel<<<dim3(B_SZ, 32), 256, 0, stream>>>(mz, value, attn, ctx);
}

// Round 4
// 324.276 us; speedup vs baseline: 1.1289x; 1.0379x over previous
//
#include <hip/hip_runtime.h>

#define B_SZ 16
#define S_SZ 8192
#define H_SZ 256

typedef _Float16 half8 __attribute__((ext_vector_type(8)));
typedef float f32x4 __attribute__((ext_vector_type(4)));

__device__ __forceinline__ float tanh_fast(float x) {
  // tanh(x) = 1 - 2/(e^{2x}+1); saturates correctly at +-inf.
  float e = __expf(2.0f * x);
  return 1.0f - 2.0f / (e + 1.0f);
}

// Monotone float<->uint map for atomicMax on signed floats.
__device__ __forceinline__ unsigned map_f(float f) {
  unsigned u = __float_as_uint(f);
  return (u & 0x80000000u) ? ~u : (u | 0x80000000u);
}
__device__ __forceinline__ float unmap_f(unsigned u) {
  unsigned b = (u & 0x80000000u) ? (u ^ 0x80000000u) : ~u;
  return __uint_as_float(b);
}

// ---------------------------------------------------------------------------
// Phase A: qb[b,o] = dot(query[b,:], Wq[o,:]) + b_attn[o]  (qb -> ctx slot,
// consumed by scores, then zeroed by reduce). Also inits mzu / Z in d_ws.
// ---------------------------------------------------------------------------
__global__ __launch_bounds__(256) void prep_kernel(
    const float* __restrict__ query, const float* __restrict__ W_attn,
    const float* __restrict__ b_attn, float* __restrict__ qb,
    unsigned* __restrict__ mzu, float* __restrict__ Zf) {
  const int b = blockIdx.x;
  const int jo = blockIdx.y;
  const int wid = threadIdx.x >> 6;
  const int lane = threadIdx.x & 63;
  const float4 q4 = *(const float4*)(query + b * H_SZ + lane * 4);
#pragma unroll 4
  for (int i = 0; i < 16; i++) {
    const int o = jo * 64 + wid * 16 + i;
    const float4 w = *(const float4*)(W_attn + (size_t)o * 512 + lane * 4);
    float p = q4.x * w.x + q4.y * w.y + q4.z * w.z + q4.w * w.w;
#pragma unroll
    for (int off = 32; off >= 1; off >>= 1) p += __shfl_xor(p, off, 64);
    if (lane == 0) qb[b * H_SZ + o] = p + b_attn[o];
  }
  if (jo == 0 && threadIdx.x == 0) {
    mzu[b] = 0u;   // mapped -NaN sentinel: smaller than any mapped real
    Zf[b] = 0.f;
  }
}

// ---------------------------------------------------------------------------
// Phase B: scores[r] = sum_o v[o]*tanh(qb[b,o] + key[r,:].Wk[o,:])
// Operand-swapped streaming GEMM: Wk lives in REGISTERS (A-operand, one
// 16-o tile per wave, loaded once); key STREAMS through double-buffered LDS
// (B-operand) in 32-row chunks. Loads for chunk c+1 are issued before
// computing chunk c -> memory/compute overlap every iteration.
// 512 blocks x 1024 threads (16 waves); 256 rows/block, 8 chunks.
// D[m = o-in-tile][col = key-row]: per-lane tanh/v-fold over 4 o's, 2
// shuffles over quads, LDS atomicAdd into psum[row]. Per-block max ->
// device atomicMax (uint-mapped) for softmax.
// ---------------------------------------------------------------------------
__global__ __launch_bounds__(1024, 4) void scores_kernel(
    const float* __restrict__ key, const float* __restrict__ W_attn,
    const float* __restrict__ qb, const float* __restrict__ vvec,
    float* __restrict__ scores, unsigned* __restrict__ mzu) {
  __shared__ _Float16 kbuf[2][32 * 256];  // 2 x 16 KiB
  __shared__ float psum[2][32];

  const int tid = threadIdx.x;
  const int wid = tid >> 6;    // o-tile index, 0..15
  const int lane = tid & 63;
  const int n = lane & 15;     // A row (o within tile) / D column (key row)
  const int quad = lane >> 4;
  const int rowBase = blockIdx.x * 256;
  const int b = rowBase >> 13;  // 256 | 8192 -> single batch per block

  // A fragments: Wk[o = wid*16 + n][k], k = ks*32 + quad*8 + j. Loaded once.
  half8 afrag[8];
  {
    const float* wrow = W_attn + (size_t)(wid * 16 + n) * 512 + 256 + quad * 8;
#pragma unroll
    for (int ks = 0; ks < 8; ks++) {
      float4 f0 = *(const float4*)(wrow + ks * 32);
      float4 f1 = *(const float4*)(wrow + ks * 32 + 4);
      half8 a;
      a[0] = (_Float16)f0.x; a[1] = (_Float16)f0.y;
      a[2] = (_Float16)f0.z; a[3] = (_Float16)f0.w;
      a[4] = (_Float16)f1.x; a[5] = (_Float16)f1.y;
      a[6] = (_Float16)f1.z; a[7] = (_Float16)f1.w;
      afrag[ks] = a;
    }
  }
  // Epilogue constants: this lane holds D rows m = quad*4+rg -> o = wid*16+m.
  float qbv[4], vvv[4];
#pragma unroll
  for (int rg = 0; rg < 4; rg++) {
    qbv[rg] = qb[b * H_SZ + wid * 16 + quad * 4 + rg];
    vvv[rg] = vvec[wid * 16 + quad * 4 + rg];
  }

  if (tid < 64) ((float*)psum)[tid] = 0.f;

  // Staging geometry: 1024 threads = 32 rows x 32 segs (8 f32 each).
  const int srow = tid >> 5;
  const int sseg = tid & 31;
  const size_t sbase = (size_t)(rowBase + srow) * H_SZ + sseg * 8;
  const int sdst = srow * 256 + ((sseg ^ srow) << 3);  // XOR-swizzled

  // Prologue: stage chunk 0.
  {
    float4 f0 = *(const float4*)(key + sbase);
    float4 f1 = *(const float4*)(key + sbase + 4);
    half8 h;
    h[0] = (_Float16)f0.x; h[1] = (_Float16)f0.y;
    h[2] = (_Float16)f0.z; h[3] = (_Float16)f0.w;
    h[4] = (_Float16)f1.x; h[5] = (_Float16)f1.y;
    h[6] = (_Float16)f1.z; h[7] = (_Float16)f1.w;
    *(half8*)&kbuf[0][sdst] = h;
  }
  __syncthreads();

  float pmax = -1e30f;

  for (int c = 0; c < 8; c++) {
    // Issue next chunk's loads (in flight during compute below).
    float4 g0, g1;
    if (c < 7) {
      const size_t nb = sbase + (size_t)(c + 1) * 32 * H_SZ;
      g0 = *(const float4*)(key + nb);
      g1 = *(const float4*)(key + nb + 4);
    }
    const _Float16* kb = kbuf[c & 1];
#pragma unroll
    for (int rt = 0; rt < 2; rt++) {
      const int lrow = rt * 16 + n;  // key row within chunk (D column)
      f32x4 acc = {0.f, 0.f, 0.f, 0.f};
#pragma unroll
      for (int ks = 0; ks < 8; ks++) {
        half8 bfrag =
            *(const half8*)&kb[lrow * 256 + (((ks * 4 + quad) ^ lrow) << 3)];
        acc = __builtin_amdgcn_mfma_f32_16x16x32_f16(afrag[ks], bfrag, acc,
                                                     0, 0, 0);
      }
      float p = 0.f;
#pragma unroll
      for (int rg = 0; rg < 4; rg++)
        p = fmaf(vvv[rg], tanh_fast(qbv[rg] + acc[rg]), p);
      // Sum over the 4 quads (same key row, different o-subsets).
      p += __shfl_xor(p, 16, 64);
      p += __shfl_xor(p, 32, 64);
      if (quad == 0) atomicAdd(&psum[c & 1][lrow], p);
    }
    if (c < 7) {  // cvt + publish chunk c+1
      half8 h;
      h[0] = (_Float16)g0.x; h[1] = (_Float16)g0.y;
      h[2] = (_Float16)g0.z; h[3] = (_Float16)g0.w;
      h[4] = (_Float16)g1.x; h[5] = (_Float16)g1.y;
      h[6] = (_Float16)g1.z; h[7] = (_Float16)g1.w;
      *(half8*)&kbuf[(c + 1) & 1][sdst] = h;
    }
    __syncthreads();
    // Write out chunk c's 32 scores; reset psum slot; track block max.
    if (tid < 32) {
      float val = psum[c & 1][tid];
      scores[rowBase + c * 32 + tid] = val;
      pmax = fmaxf(pmax, val);
      psum[c & 1][tid] = 0.f;
    }
  }
  if (wid == 0) {
#pragma unroll
    for (int off = 32; off >= 1; off >>= 1)
      pmax = fmaxf(pmax, __shfl_xor(pmax, off, 64));
    if (lane == 0) atomicMax(&mzu[b], map_f(pmax));
  }
}

// ---------------------------------------------------------------------------
// Phase C: Z[b] = sum_s exp(score - m). 256 blocks (16 per batch), 512
// scores each, one atomicAdd per block. Also zeroes the context slot.
// ---------------------------------------------------------------------------
__global__ __launch_bounds__(256) void reduce_kernel(
    const float* __restrict__ scores, const unsigned* __restrict__ mzu,
    float* __restrict__ Zf, float* __restrict__ ctx) {
  const int b = blockIdx.x >> 4;
  const int j = blockIdx.x & 15;
  const int tid = threadIdx.x;
  const float m = unmap_f(mzu[b]);
  const float* s = scores + b * S_SZ + j * 512;
  float part = __expf(s[tid] - m) + __expf(s[tid + 256] - m);
#pragma unroll
  for (int off = 32; off >= 1; off >>= 1) part += __shfl_xor(part, off, 64);
  __shared__ float red[4];
  if ((tid & 63) == 0) red[tid >> 6] = part;
  __syncthreads();
  if (tid == 0) atomicAdd(&Zf[b], red[0] + red[1] + red[2] + red[3]);
  if (tid < 16) ctx[b * H_SZ + j * 16 + tid] = 0.f;
}

// ---------------------------------------------------------------------------
// Phase D: w = exp(score-m)/Z (written to attn in place); context[b,h] +=
// sum_s w*value[b,s,h]. Grid (16,32), 256 threads: 4 s-groups x 64 float4
// h-lanes; LDS combine; 4 atomics per h4 per block.
// ---------------------------------------------------------------------------
__global__ __launch_bounds__(256) void context_kernel(
    const unsigned* __restrict__ mzu, const float* __restrict__ Zf,
    const float* __restrict__ value, float* __restrict__ attn,
    float* __restrict__ ctx) {
  __shared__ float wsm[256];
  __shared__ float4 psum4[3][64];
  const int b = blockIdx.x;
  const int j = blockIdx.y;
  const int t = threadIdx.x;
  const int g = t >> 6;   // s-group 0..3
  const int hl = t & 63;  // float4 column
  const int s0 = j * 256;
  const float m = unmap_f(mzu[b]);
  const float invZ = 1.0f / Zf[b];
  float* arow = attn + b * S_SZ + s0;
  const float w = __expf(arow[t] - m) * invZ;
  arow[t] = w;  // attn_weights output
  wsm[t] = w;
  __syncthreads();
  const float4* vp =
      (const float4*)value + ((size_t)(b * S_SZ + s0 + g * 64)) * 64 + hl;
  float4 acc = {0.f, 0.f, 0.f, 0.f};
#pragma unroll 8
  for (int s = 0; s < 64; s++) {
    const float ww = wsm[g * 64 + s];
    const float4 vv = vp[(size_t)s * 64];
    acc.x = fmaf(ww, vv.x, acc.x);
    acc.y = fmaf(ww, vv.y, acc.y);
    acc.z = fmaf(ww, vv.z, acc.z);
    acc.w = fmaf(ww, vv.w, acc.w);
  }
  if (g > 0) psum4[g - 1][hl] = acc;
  __syncthreads();
  if (g == 0) {
    const float4 a1 = psum4[0][hl], a2 = psum4[1][hl], a3 = psum4[2][hl];
    acc.x += a1.x + a2.x + a3.x;
    acc.y += a1.y + a2.y + a3.y;
    acc.z += a1.z + a2.z + a3.z;
    acc.w += a1.w + a2.w + a3.w;
    float* cp = ctx + b * H_SZ + hl * 4;
    atomicAdd(cp + 0, acc.x);
    atomicAdd(cp + 1, acc.y);
    atomicAdd(cp + 2, acc.z);
    atomicAdd(cp + 3, acc.w);
  }
}

// ---------------------------------------------------------------------------
extern "C" void kernel_launch(void* const* d_in, const int* in_sizes, int n_in,
                              void* d_out, int out_size, void* d_ws,
                              size_t ws_size, hipStream_t stream) {
  const float* query = (const float*)d_in[0];   // (16,1,256)
  const float* key = (const float*)d_in[1];     // (16,8192,256)
  const float* value = (const float*)d_in[2];   // (16,8192,256)
  const float* W_attn = (const float*)d_in[3];  // (256,512)
  const float* b_attn = (const float*)d_in[4];  // (256,)
  const float* vvec = (const float*)d_in[5];    // (256,)

  float* out = (float*)d_out;
  float* ctx = out;          // 16*256 (qb scratch, then context via atomics)
  float* attn = out + 4096;  // 16*8192 (raw scores -> weights in place)
  unsigned* mzu = (unsigned*)d_ws;      // 16 mapped-uint maxes
  float* Zf = (float*)d_ws + 16;        // 16 partition sums

  prep_kernel<<<dim3(B_SZ, 4), 256, 0, stream>>>(query, W_attn, b_attn, ctx,
                                                 mzu, Zf);
  scores_kernel<<<512, 1024, 0, stream>>>(key, W_attn, ctx, vvec, attn, mzu);
  reduce_kernel<<<256, 256, 0, stream>>>(attn, mzu, Zf, ctx);
  context_kernel<<<dim3(B_SZ, 32), 256, 0, stream>>>(mzu, Zf, value, attn,
                                                     ctx);
}